// Round 14
// baseline (32332.492 us; speedup 1.0000x reference)
//
#include <hip/hip_runtime.h>
#include <math.h>

#define B 256
#define T 512
#define H 1024
#define NBLK 256

typedef _Float16 f16x8 __attribute__((ext_vector_type(8)));
typedef float f32x4 __attribute__((ext_vector_type(4)));
typedef unsigned u32x4 __attribute__((ext_vector_type(4)));

__device__ __forceinline__ float sigmoidf_(float x) { return 1.0f / (1.0f + __expf(-x)); }
__device__ __forceinline__ float tanhf_(float x) {
    float ax = fabsf(x);
    float t = __expf(-2.0f * ax);
    float r = (1.0f - t) / (1.0f + t);
    return x < 0.f ? -r : r;
}

// ---- agent-coherent access (write-through LLC, bypass L1/L2; no fences) ----
__device__ __forceinline__ void store_b128_coh(void* p, u32x4 v) {
    asm volatile("global_store_dwordx4 %0, %1, off sc0 sc1" :: "v"(p), "v"(v) : "memory");
}
__device__ __forceinline__ u32x4 load_b16_coh(const void* p) {
    u32x4 v;
    asm volatile("global_load_dwordx4 %0, %1, off sc0 sc1" : "=v"(v) : "v"(p));
    return v;
}
__device__ __forceinline__ unsigned load_tag(const unsigned* p) {
    return __hip_atomic_load((unsigned*)p, __ATOMIC_RELAXED, __HIP_MEMORY_SCOPE_AGENT);
}

// ---- intra-sub barrier: 8 waves, LDS monotone counter (no __syncthreads!) ----
// bar[0] = arrival count (never reset), bar[1] = completed-barrier generation.
// nb = 1-based barrier index, maintained identically by all 8 waves of the sub.
// lgkmcnt(0) drains this wave's LDS writes before arrival; trailing compiler
// fence + sched_barrier stop hoisting of subsequent LDS reads above the spin.
__device__ __forceinline__ void sbar(unsigned* bar, int lane, unsigned nb) {
    asm volatile("s_waitcnt lgkmcnt(0)" ::: "memory");
    if (lane == 0) {
        unsigned old = __hip_atomic_fetch_add(&bar[0], 1u, __ATOMIC_RELAXED,
                                              __HIP_MEMORY_SCOPE_WORKGROUP);
        if (old + 1u == nb * 8u) {
            __hip_atomic_store(&bar[1], nb, __ATOMIC_RELAXED, __HIP_MEMORY_SCOPE_WORKGROUP);
        } else {
            while (__hip_atomic_load(&bar[1], __ATOMIC_RELAXED,
                                     __HIP_MEMORY_SCOPE_WORKGROUP) < nb)
                __builtin_amdgcn_s_sleep(1);
        }
    }
    asm volatile("" ::: "memory");
    __builtin_amdgcn_sched_barrier(0);
}

// Load this wave's 48 B-fragments (3 gates x 16 k-chunks of its K-half),
// f32 -> f16. j = this lane's B row; one-time cost.
__device__ __forceinline__ void load_weights(f16x8 (&wB)[48], const float* __restrict__ W,
                                             int j, int kh, int kg) {
#pragma unroll
    for (int g = 0; g < 3; ++g)
#pragma unroll
        for (int i = 0; i < 16; ++i) {
            const float* p = W + (((size_t)g << 10) + j) * 1024 + (kh << 9) + (i << 5) + (kg << 3);
            float4 u = *(const float4*)p;
            float4 v = *(const float4*)(p + 4);
            f16x8 o;
            o[0] = (_Float16)u.x; o[1] = (_Float16)u.y; o[2] = (_Float16)u.z; o[3] = (_Float16)u.w;
            o[4] = (_Float16)v.x; o[5] = (_Float16)v.y; o[6] = (_Float16)v.z; o[7] = (_Float16)v.w;
            wB[g * 16 + i] = o;
        }
}

// Stage this sub's 8x1024 f16 A-tile from HPTR into Als (XOR-swizzled).
#define STAGE_TILE(HPTR)                                                                   \
    do {                                                                                   \
        int c0 = tid_s, c1 = tid_s + 512;                                                  \
        int r0 = c0 >> 7, r1 = c1 >> 7;                                                    \
        u32x4 v0 = load_b16_coh((HPTR) + ((size_t)(b0s + r0) << 10) + ((c0 & 127) << 3));  \
        u32x4 v1 = load_b16_coh((HPTR) + ((size_t)(b0s + r1) << 10) + ((c1 & 127) << 3));  \
        asm volatile("s_waitcnt vmcnt(0)" ::: "memory");                                   \
        __builtin_amdgcn_sched_barrier(0);                                                 \
        *(u32x4*)(Als + r0 * 2048 + (((c0 & 127) << 4) ^ ((r0 & 7) << 4))) = v0;           \
        *(u32x4*)(Als + r1 * 2048 + (((c1 & 127) << 4) ^ ((r1 & 7) << 4))) = v1;           \
    } while (0)

#define POLL_TAGS(G)                                                                       \
    do {                                                                                   \
        if (lane < 16) {                                                                   \
            while (load_tag(mytags + lane * 32) < (G)) __builtin_amdgcn_s_sleep(1);        \
        }                                                                                  \
        __builtin_amdgcn_sched_barrier(0);                                                 \
    } while (0)

// Publisher = wave 7 of the sub: 64 lanes x 16B = the sub's 8x64 f16 slice.
#define PUBLISH_TAG(HN, G)                                                                 \
    do {                                                                                   \
        if (w3 == 7) {                                                                     \
            int prow = lane >> 3, pc = lane & 7;                                           \
            store_b128_coh((HN) + ((size_t)(b0s + prow) << 10) + j0 + pc * 8,              \
                           *(const u32x4*)&hout[prow][pc * 8]);                            \
            asm volatile("s_waitcnt vmcnt(0)" ::: "memory");                               \
            if (lane == 0)                                                                 \
                __hip_atomic_store(mytags + ownoff, (G), __ATOMIC_RELAXED,                 \
                                   __HIP_MEMORY_SCOPE_AGENT);                              \
        }                                                                                  \
    } while (0)

// x-partials from the staged tile: kh0 waves, lane -> (row=lane>>3, k-slice).
// Result: xps[np][row] = partial dot(h[row], Wout) over np's K-quarter.
#define XPARTIAL()                                                                         \
    do {                                                                                   \
        if (kh == 0) {                                                                     \
            const int xr = lane >> 3, kc8 = lane & 7;                                      \
            float p = 0.f;                                                                 \
            _Pragma("unroll")                                                              \
            for (int q = 0; q < 4; ++q) {                                                  \
                int kf = np * 256 + kc8 * 32 + q * 8;                                      \
                f16x8 hv = *(const f16x8*)(Als + xr * 2048 + ((kf * 2) ^ ((xr & 7) << 4)));\
                _Pragma("unroll")                                                          \
                for (int e = 0; e < 8; ++e) p += (float)hv[e] * wout32[q * 8 + e];         \
            }                                                                              \
            p += __shfl_xor(p, 1); p += __shfl_xor(p, 2); p += __shfl_xor(p, 4);           \
            if (kc8 == 0) xps[np][xr] = p;                                                 \
        }                                                                                  \
    } while (0)

__global__ __launch_bounds__(1024, 4) void gru_persistent(
    const float* __restrict__ input, const float* __restrict__ h_init,
    const float* __restrict__ Wih_e, const float* __restrict__ Whh_e,
    const float* __restrict__ bih_e, const float* __restrict__ bhh_e,
    const float* __restrict__ Wenc, const float* __restrict__ benc,
    const float* __restrict__ Wdec, const float* __restrict__ bdec,
    const float* __restrict__ Wih_d, const float* __restrict__ Whh_d,
    const float* __restrict__ bih_d, const float* __restrict__ bhh_d,
    const float* __restrict__ Wout, const float* __restrict__ boutp,
    float* __restrict__ featOut, float* __restrict__ outp,
    _Float16* __restrict__ h16A, _Float16* __restrict__ h16B,
    unsigned* tags)
{
    __shared__ __align__(16) char Als2[2][16384];
    __shared__ f32x4 red2[2][4][3][64];
    __shared__ __align__(16) _Float16 hout2[2][8][64];
    __shared__ float xps2[2][4][8];
    __shared__ float fps2[2][4][8][3];
    __shared__ float feats2[2][8][3];
    __shared__ unsigned bars[2][8];

    const int tid = threadIdx.x;
    const int lane = tid & 63;
    const int wv = tid >> 6;          // 0..15
    const int sub = wv >> 3;          // 0,1: independent half-batch pipelines
    const int w3 = wv & 7;            // wave within sub
    const int kh = w3 & 1;            // K-half
    const int np = w3 >> 1;           // n-quadrant 0..3
    const int kg = lane >> 4;         // 0..3
    const int r16 = lane & 15;
    const int tid_s = w3 * 64 + lane; // sub-local thread id 0..511
    const int bid = blockIdx.x;
    const int bt = bid & 15, jt = bid >> 4;
    const int b0s = bt * 16 + sub * 8;   // this sub's 8 batch rows
    const int j0 = jt * 64;
    const int j = j0 + np * 16 + r16;
    const float bout_v = boutp[0];

    char* Als = Als2[sub];
    f32x4 (*red)[3][64] = red2[sub];
    _Float16 (*hout)[64] = hout2[sub];
    float (*xps)[8] = xps2[sub];
    float (*fps)[8][3] = fps2[sub];
    float (*feats)[3] = feats2[sub];
    unsigned* bar = bars[sub];
    unsigned* mytags = tags + (size_t)(bt * 32 + sub * 16) * 32;
    const unsigned ownoff = (unsigned)jt * 32;

    unsigned gcur = 0, nb = 0;
    f16x8 wB[48];
    float hreg[4] = {0.f, 0.f, 0.f, 0.f};
    float wout32[32];
#pragma unroll
    for (int i = 0; i < 32; ++i) wout32[i] = 0.f;

    // ---- one-time LDS init + the ONLY full-block barrier ----
    if (tid < 16) bars[tid >> 3][tid & 7] = 0u;
    __syncthreads();

    // ---- init: hreg + hout from h_init; publish to h16A (tag 1) ----
    if (kh == 0 && kg < 2) {
#pragma unroll
        for (int reg = 0; reg < 4; ++reg) {
            int row = kg * 4 + reg;
            float v = h_init[((size_t)(b0s + row) << 10) + j];
            hreg[reg] = v;
            hout[row][np * 16 + r16] = (_Float16)v;
        }
    }
    sbar(bar, lane, ++nb);
    PUBLISH_TAG(h16A, gcur + 1);
    ++gcur;   // = 1
    load_weights(wB, Whh_e, j, kh, kg);

    // =================== the two phases (runtime DEC flag) ===================
    auto phase = [&](bool DEC, _Float16* bufE, _Float16* bufO,
                     const float* Wih, const float* bih, const float* bhh) {
        const float wi_r = Wih[j], wi_z = Wih[H + j], wi_n = Wih[2 * H + j];
        const float bi_r = bih[j], bi_z = bih[H + j], bi_n = bih[2 * H + j];
        const float bh_r = bhh[j], bh_z = bhh[H + j], bh_n = bhh[2 * H + j];

        for (int t = 0; t < T; ++t) {
            const _Float16* hp = (t & 1) ? bufO : bufE;
            _Float16* hn = (t & 1) ? bufE : bufO;
            const unsigned g = gcur;

            POLL_TAGS(g);
            STAGE_TILE(hp);
            sbar(bar, lane, ++nb);      // tile ready

            if (DEC) XPARTIAL();

            // ---- MFMA: 3 gates x K-half; A rows mirrored (r16&7) ----
            f32x4 aR = {0.f, 0.f, 0.f, 0.f}, aZ = {0.f, 0.f, 0.f, 0.f},
                  aN = {0.f, 0.f, 0.f, 0.f};
#pragma unroll
            for (int i = 0; i < 16; ++i) {
                int kb = (kh << 10) + (i << 6) + (kg << 4);
                int ar = r16 & 7;
                f16x8 a = *(const f16x8*)(Als + (ar << 11) + (kb ^ (ar << 4)));
                aR = __builtin_amdgcn_mfma_f32_16x16x32_f16(a, wB[i], aR, 0, 0, 0);
                aZ = __builtin_amdgcn_mfma_f32_16x16x32_f16(a, wB[16 + i], aZ, 0, 0, 0);
                aN = __builtin_amdgcn_mfma_f32_16x16x32_f16(a, wB[32 + i], aN, 0, 0, 0);
            }
            if (kh == 1) {
                red[np][0][lane] = aR; red[np][1][lane] = aZ; red[np][2][lane] = aN;
            }
            sbar(bar, lane, ++nb);      // red + xps ready

            if (kh == 0) {
                f32x4 rR = red[np][0][lane], rZ = red[np][1][lane], rN = red[np][2][lane];
                if (kg < 2) {
#pragma unroll
                    for (int reg = 0; reg < 4; ++reg) {
                        int row = kg * 4 + reg;
                        float xv;
                        if (DEC)
                            xv = (t > 0) ? (xps[0][row] + xps[1][row] + xps[2][row] +
                                            xps[3][row] + bout_v)
                                         : 0.f;
                        else
                            xv = input[(size_t)(b0s + row) * T + t];
                        float r = sigmoidf_(xv * wi_r + bi_r + aR[reg] + rR[reg] + bh_r);
                        float z = sigmoidf_(xv * wi_z + bi_z + aZ[reg] + rZ[reg] + bh_z);
                        float n = tanhf_(xv * wi_n + bi_n + r * (aN[reg] + rN[reg] + bh_n));
                        float hNew = (1.f - z) * n + z * hreg[reg];
                        hreg[reg] = hNew;
                        hout[row][np * 16 + r16] = (_Float16)hNew;
                        if (DEC && t > 0 && np == 0 && r16 == 0 && jt == 0)
                            outp[(size_t)(b0s + row) * T + (t - 1)] = xv;
                    }
                }
            }
            sbar(bar, lane, ++nb);      // hout ready

            PUBLISH_TAG(hn, g + 1);
            ++gcur;
        }
    };

    // ---- encoder: reads A at even t (h_init in A), T=512 steps ----
    phase(false, h16A, h16B, Wih_e, bih_e, bhh_e);
    // gcur = 513; h_T in h16A (t=511 wrote bufE=h16A)

    // ---- bottleneck (per sub, row-local): stage h_T, features, h0 ----
    {
        const unsigned g = gcur;        // 513
        POLL_TAGS(g);
        STAGE_TILE(h16A);
        sbar(bar, lane, ++nb);

        if (kh == 0) {
            const int xr = lane >> 3, kc8 = lane & 7;
            float p0 = 0.f, p1 = 0.f, p2 = 0.f;
#pragma unroll
            for (int q = 0; q < 4; ++q) {
                int kf = np * 256 + kc8 * 32 + q * 8;
                f16x8 hv = *(const f16x8*)(Als + xr * 2048 + ((kf * 2) ^ ((xr & 7) << 4)));
#pragma unroll
                for (int e = 0; e < 8; ++e) {
                    float hvv = (float)hv[e];
                    p0 += hvv * Wenc[kf + e];
                    p1 += hvv * Wenc[H + kf + e];
                    p2 += hvv * Wenc[2 * H + kf + e];
                }
            }
            p0 += __shfl_xor(p0, 1); p0 += __shfl_xor(p0, 2); p0 += __shfl_xor(p0, 4);
            p1 += __shfl_xor(p1, 1); p1 += __shfl_xor(p1, 2); p1 += __shfl_xor(p1, 4);
            p2 += __shfl_xor(p2, 1); p2 += __shfl_xor(p2, 2); p2 += __shfl_xor(p2, 4);
            if (kc8 == 0) {
                fps[np][xr][0] = p0; fps[np][xr][1] = p1; fps[np][xr][2] = p2;
            }
        }
        sbar(bar, lane, ++nb);

        if (w3 == 0 && lane < 24) {
            int bi = lane / 3, c = lane % 3;
            float s = fps[0][bi][c] + fps[1][bi][c] + fps[2][bi][c] + fps[3][bi][c] + benc[c];
            float f = sigmoidf_(s);
            feats[bi][c] = f;
            if (jt == 0) featOut[(b0s + bi) * 3 + c] = f;
        }
        sbar(bar, lane, ++nb);

        if (kh == 0 && kg < 2) {
#pragma unroll
            for (int reg = 0; reg < 4; ++reg) {
                int row = kg * 4 + reg;
                float v = feats[row][0] * Wdec[j * 3 + 0] + feats[row][1] * Wdec[j * 3 + 1] +
                          feats[row][2] * Wdec[j * 3 + 2] + bdec[j];
                hreg[reg] = v;
                hout[row][np * 16 + r16] = (_Float16)v;
            }
        }
        sbar(bar, lane, ++nb);

        PUBLISH_TAG(h16B, g + 1);       // h0 -> B (decoder reads B at even t)
        ++gcur;                          // 514
    }

    load_weights(wB, Whh_d, j, kh, kg);
    if (kh == 0) {
#pragma unroll
        for (int q = 0; q < 8; ++q) {
            f32x4 w4 = *(const f32x4*)(Wout + np * 256 + (lane & 7) * 32 + q * 4);
            wout32[q * 4 + 0] = w4[0]; wout32[q * 4 + 1] = w4[1];
            wout32[q * 4 + 2] = w4[2]; wout32[q * 4 + 3] = w4[3];
        }
    }

    // ---- decoder: reads B at even t (h0 in B), T=512 steps ----
    phase(true, h16B, h16A, Wih_d, bih_d, bhh_d);
    // gcur = 1026; h_T(dec) in h16B (t=511 wrote bufE=h16B)

    // ---- final column: out[:, T-1] = h_T . Wout + bout ----
    {
        const unsigned g = gcur;        // 1026
        POLL_TAGS(g);
        STAGE_TILE(h16B);
        sbar(bar, lane, ++nb);
        XPARTIAL();
        sbar(bar, lane, ++nb);
        if (kh == 0 && kg < 2 && np == 0 && r16 == 0 && jt == 0) {
#pragma unroll
            for (int reg = 0; reg < 4; ++reg) {
                int row = kg * 4 + reg;
                float xv = xps[0][row] + xps[1][row] + xps[2][row] + xps[3][row] + bout_v;
                outp[(size_t)(b0s + row) * T + (T - 1)] = xv;
            }
        }
    }
}

__global__ __launch_bounds__(256) void loss_partial(
    const float* __restrict__ input, const float* __restrict__ outp,
    float* __restrict__ partial)
{
    int idx = blockIdx.x * blockDim.x + threadIdx.x;
    float s = 0.f;
    for (int i = idx; i < B * T; i += gridDim.x * blockDim.x) {
        float d = input[i] - outp[i];
        s += d * d;
    }
#pragma unroll
    for (int off = 32; off; off >>= 1) s += __shfl_down(s, off);
    __shared__ float ws[4];
    if ((threadIdx.x & 63) == 0) ws[threadIdx.x >> 6] = s;
    __syncthreads();
    if (threadIdx.x == 0) partial[blockIdx.x] = ws[0] + ws[1] + ws[2] + ws[3];
}

__global__ __launch_bounds__(256) void loss_final(
    const float* __restrict__ partial, float* __restrict__ loss)
{
    int tid = threadIdx.x;
    float s = partial[tid];
#pragma unroll
    for (int off = 32; off; off >>= 1) s += __shfl_down(s, off);
    __shared__ float ws[4];
    if ((tid & 63) == 0) ws[tid >> 6] = s;
    __syncthreads();
    if (tid == 0) loss[0] = (ws[0] + ws[1] + ws[2] + ws[3]) * (1.0f / (float)(B * T));
}

extern "C" void kernel_launch(void* const* d_in, const int* in_sizes, int n_in,
                              void* d_out, int out_size, void* d_ws, size_t ws_size,
                              hipStream_t stream) {
    const float* input = (const float*)d_in[0];
    const float* h_init = (const float*)d_in[1];
    const float* Wih_e = (const float*)d_in[2];
    const float* Whh_e = (const float*)d_in[3];
    const float* bih_e = (const float*)d_in[4];
    const float* bhh_e = (const float*)d_in[5];
    const float* Wenc  = (const float*)d_in[6];
    const float* benc  = (const float*)d_in[7];
    const float* Wdec  = (const float*)d_in[8];
    const float* bdec  = (const float*)d_in[9];
    const float* Wih_d = (const float*)d_in[10];
    const float* Whh_d = (const float*)d_in[11];
    const float* bih_d = (const float*)d_in[12];
    const float* bhh_d = (const float*)d_in[13];
    const float* Wout  = (const float*)d_in[14];
    const float* bout  = (const float*)d_in[15];
    (void)in_sizes; (void)n_in; (void)out_size; (void)ws_size;

    float* out = (float*)d_out;
    float* lossp = out;                    // [1]
    float* feat = out + 1;                 // [B*3]
    float* outp = out + 1 + B * 3;         // [B*T]

    // ---- workspace layout ----
    char* ws = (char*)d_ws;
    _Float16* h16A = (_Float16*)ws;                  ws += (size_t)B * H * 2;
    _Float16* h16B = (_Float16*)ws;                  ws += (size_t)B * H * 2;
    float* partial = (float*)ws;                     ws += 256 * 4;
    ws = (char*)(((uintptr_t)ws + 127) & ~(uintptr_t)127);
    unsigned* tags = (unsigned*)ws;                  ws += 512 * 32 * 4;  // [bt][sub][jt] padded

    // tags must start at 0 every call (ws poisoned once, not restored)
    hipMemsetAsync(tags, 0, 512 * 32 * 4, stream);

    gru_persistent<<<dim3(NBLK), dim3(1024), 0, stream>>>(
        input, h_init, Wih_e, Whh_e, bih_e, bhh_e, Wenc, benc, Wdec, bdec,
        Wih_d, Whh_d, bih_d, bhh_d, Wout, bout,
        feat, outp, h16A, h16B, tags);

    loss_partial<<<256, 256, 0, stream>>>(input, outp, partial);
    loss_final<<<1, 256, 0, stream>>>(partial, lossp);
}

// Round 16
// 30885.361 us; speedup vs baseline: 1.0469x; 1.0469x over previous
//
#include <hip/hip_runtime.h>
#include <math.h>

#define B 256
#define T 512
#define H 1024
#define NBLK 256

typedef _Float16 f16x8 __attribute__((ext_vector_type(8)));
typedef float f32x4 __attribute__((ext_vector_type(4)));
typedef unsigned u32x4 __attribute__((ext_vector_type(4)));

__device__ __forceinline__ float sigmoidf_(float x) { return 1.0f / (1.0f + __expf(-x)); }
__device__ __forceinline__ float tanhf_(float x) {
    float ax = fabsf(x);
    float t = __expf(-2.0f * ax);
    float r = (1.0f - t) / (1.0f + t);
    return x < 0.f ? -r : r;
}

// ---- agent-coherent access (write-through LLC, bypass L1/L2; no fences) ----
__device__ __forceinline__ void store_b128_coh(void* p, u32x4 v) {
    asm volatile("global_store_dwordx4 %0, %1, off sc0 sc1" :: "v"(p), "v"(v) : "memory");
}
__device__ __forceinline__ u32x4 load_b16_coh(const void* p) {
    u32x4 v;
    asm volatile("global_load_dwordx4 %0, %1, off sc0 sc1" : "=v"(v) : "v"(p));
    return v;
}
__device__ __forceinline__ unsigned load_tag(const unsigned* p) {
    return __hip_atomic_load((unsigned*)p, __ATOMIC_RELAXED, __HIP_MEMORY_SCOPE_AGENT);
}
__device__ __forceinline__ void store_tag(unsigned* p, unsigned v) {
    __hip_atomic_store(p, v, __ATOMIC_RELAXED, __HIP_MEMORY_SCOPE_AGENT);
}

// ---- intra-pipeline barrier: 4 waves, LDS monotone counter (R14-proven) ----
// bar[0] = arrival count (never reset), bar[1] = completed generation.
__device__ __forceinline__ void sbar4(unsigned* bar, int lane, unsigned nb) {
    asm volatile("s_waitcnt lgkmcnt(0)" ::: "memory");
    if (lane == 0) {
        unsigned old = __hip_atomic_fetch_add(&bar[0], 1u, __ATOMIC_RELAXED,
                                              __HIP_MEMORY_SCOPE_WORKGROUP);
        if (old + 1u == nb * 4u) {
            __hip_atomic_store(&bar[1], nb, __ATOMIC_RELAXED, __HIP_MEMORY_SCOPE_WORKGROUP);
        } else {
            while (__hip_atomic_load(&bar[1], __ATOMIC_RELAXED,
                                     __HIP_MEMORY_SCOPE_WORKGROUP) < nb)
                __builtin_amdgcn_s_sleep(1);
        }
    }
    asm volatile("" ::: "memory");
    __builtin_amdgcn_sched_barrier(0);
}

// Load this wave's 96 B-fragments (3 gates x 32 K-chunks, FULL K),
// f32 -> f16. j = this lane's B row.
__device__ __forceinline__ void load_weights(f16x8 (&wB)[96], const float* __restrict__ W,
                                             int j, int kg) {
#pragma unroll
    for (int g = 0; g < 3; ++g)
#pragma unroll
        for (int i = 0; i < 32; ++i) {
            const float* p = W + (((size_t)g << 10) + j) * 1024 + (i << 5) + (kg << 3);
            float4 u = *(const float4*)p;
            float4 v = *(const float4*)(p + 4);
            f16x8 o;
            o[0] = (_Float16)u.x; o[1] = (_Float16)u.y; o[2] = (_Float16)u.z; o[3] = (_Float16)u.w;
            o[4] = (_Float16)v.x; o[5] = (_Float16)v.y; o[6] = (_Float16)v.z; o[7] = (_Float16)v.w;
            wB[g * 32 + i] = o;
        }
}

// Poll all 64 producer tags of this (bt,sub) group (64 lanes, 1 tag each).
#define POLL_OWN(G)                                                                        \
    do {                                                                                   \
        while (load_tag(mytags + lane * 16) < (G)) __builtin_amdgcn_s_sleep(1);            \
        __builtin_amdgcn_sched_barrier(0);                                                 \
    } while (0)

// Stage the pipeline's 8x1024 f16 tile from HPTR into abuf (XOR-swizzled).
#define STAGE(HPTR, abuf)                                                                  \
    do {                                                                                   \
        u32x4 sv0, sv1, sv2, sv3;                                                          \
        {                                                                                  \
            int c = tid_p;            int r = c >> 7, ch = c & 127;                        \
            sv0 = load_b16_coh((HPTR) + ((size_t)(b0s + r) << 10) + (ch << 3));            \
        }                                                                                  \
        {                                                                                  \
            int c = tid_p + 256;      int r = c >> 7, ch = c & 127;                        \
            sv1 = load_b16_coh((HPTR) + ((size_t)(b0s + r) << 10) + (ch << 3));            \
        }                                                                                  \
        {                                                                                  \
            int c = tid_p + 512;      int r = c >> 7, ch = c & 127;                        \
            sv2 = load_b16_coh((HPTR) + ((size_t)(b0s + r) << 10) + (ch << 3));            \
        }                                                                                  \
        {                                                                                  \
            int c = tid_p + 768;      int r = c >> 7, ch = c & 127;                        \
            sv3 = load_b16_coh((HPTR) + ((size_t)(b0s + r) << 10) + (ch << 3));            \
        }                                                                                  \
        asm volatile("s_waitcnt vmcnt(0)" ::: "memory");                                   \
        __builtin_amdgcn_sched_barrier(0);                                                 \
        {                                                                                  \
            int c = tid_p;            int r = c >> 7, ch = c & 127;                        \
            *(u32x4*)((abuf) + r * 2048 + ((ch << 4) ^ ((r & 7) << 4))) = sv0;             \
        }                                                                                  \
        {                                                                                  \
            int c = tid_p + 256;      int r = c >> 7, ch = c & 127;                        \
            *(u32x4*)((abuf) + r * 2048 + ((ch << 4) ^ ((r & 7) << 4))) = sv1;             \
        }                                                                                  \
        {                                                                                  \
            int c = tid_p + 512;      int r = c >> 7, ch = c & 127;                        \
            *(u32x4*)((abuf) + r * 2048 + ((ch << 4) ^ ((r & 7) << 4))) = sv2;             \
        }                                                                                  \
        {                                                                                  \
            int c = tid_p + 768;      int r = c >> 7, ch = c & 127;                        \
            *(u32x4*)((abuf) + r * 2048 + ((ch << 4) ^ ((r & 7) << 4))) = sv3;             \
        }                                                                                  \
    } while (0)

// Publish this wave's own 8-row x 16-col stripe from hout, drain, tag.
#define PUBLISH_OWN(HN, G)                                                                 \
    do {                                                                                   \
        asm volatile("s_waitcnt lgkmcnt(0)" ::: "memory");                                 \
        if (lane < 16) {                                                                   \
            int prow = lane >> 1, ph = lane & 1;                                           \
            u32x4 pv = *(const u32x4*)((const char*)&hout[0][0] +                          \
                                       prow * 128 + np * 32 + ph * 16);                    \
            store_b128_coh((HN) + ((size_t)(b0s + prow) << 10) + j0 + np * 16 + ph * 8,    \
                           pv);                                                            \
        }                                                                                  \
        asm volatile("s_waitcnt vmcnt(0)" ::: "memory");                                   \
        if (lane == 0) store_tag(mytags + ownoff, (G));                                    \
    } while (0)

__global__ __launch_bounds__(512, 1) void gru_persistent(
    const float* __restrict__ input, const float* __restrict__ h_init,
    const float* __restrict__ Wih_e, const float* __restrict__ Whh_e,
    const float* __restrict__ bih_e, const float* __restrict__ bhh_e,
    const float* __restrict__ Wenc, const float* __restrict__ benc,
    const float* __restrict__ Wdec, const float* __restrict__ bdec,
    const float* __restrict__ Wih_d, const float* __restrict__ Whh_d,
    const float* __restrict__ bih_d, const float* __restrict__ bhh_d,
    const float* __restrict__ Wout, const float* __restrict__ boutp,
    float* __restrict__ featOut, float* __restrict__ outp,
    _Float16* __restrict__ h16A, _Float16* __restrict__ h16B,
    unsigned* tags)
{
    // LDS: 2 subs x 2 step-parity buffers x 16KB + hout + bars + occupancy pad
    __shared__ __align__(16) char Als4[4][16384];      // [sub*2 + parity]
    __shared__ __align__(16) _Float16 hout2[2][8][64];
    __shared__ unsigned bars[2][2];
    __shared__ char occ_pad[16384];                    // forces 1 block/CU (>80KB total)

    const int tid = threadIdx.x;
    const int lane = tid & 63;
    const int wv = tid >> 6;       // 0..7
    const int sub = wv >> 2;       // 0,1 : independent pipelines
    const int np = wv & 3;         // n-quadrant within pipeline
    const int kg = lane >> 4;      // 0..3
    const int r16 = lane & 15;
    const int tid_p = np * 64 + lane;   // pipeline-local tid 0..255
    const int bid = blockIdx.x;
    const int bt = bid & 15, jt = bid >> 4;
    const int b0s = bt * 16 + sub * 8;  // this pipeline's 8 batch rows
    const int j0 = jt * 64;
    const int j = j0 + np * 16 + r16;
    const float bout_v = boutp[0];

    _Float16 (*hout)[64] = hout2[sub];
    unsigned* bar = bars[sub];
    unsigned* mytags = tags + (size_t)(bt * 2 + sub) * 1024;   // 64 tags x 16 dwords
    const unsigned ownoff = (unsigned)(jt * 4 + np) * 16;

    unsigned gcur = 0, nb = 0, sc = 0;
    f16x8 wB[96];
    float hreg[4] = {0.f, 0.f, 0.f, 0.f};
    float wout[16];
#pragma unroll
    for (int i = 0; i < 16; ++i) wout[i] = 0.f;

    if (tid == 0) ((volatile char*)occ_pad)[0] = 1;   // keep pad live
    if (tid < 4) ((unsigned*)bars)[tid] = 0u;
    __syncthreads();   // the only full-block barrier

    // ---- init: hreg + hout from h_init; publish to h16A (tag 1) ----
    if (kg < 2) {
#pragma unroll
        for (int reg = 0; reg < 4; ++reg) {
            int row = kg * 4 + reg;
            float v = h_init[((size_t)(b0s + row) << 10) + j];
            hreg[reg] = v;
            hout[row][np * 16 + r16] = (_Float16)v;
        }
    }
    PUBLISH_OWN(h16A, 1u);
    gcur = 1;
    load_weights(wB, Whh_e, j, kg);

    // ================= phase runner (encoder / decoder) =================
    auto phase = [&](bool DEC, _Float16* bufF, _Float16* bufS,
                     const float* Wih, const float* bih, const float* bhh) {
        const float wi_r = Wih[j], wi_z = Wih[H + j], wi_n = Wih[2 * H + j];
        const float bi_r = bih[j], bi_z = bih[H + j], bi_n = bih[2 * H + j];
        const float bh_r = bhh[j], bh_z = bhh[H + j], bh_n = bhh[2 * H + j];

        for (int t = 0; t < T; ++t) {
            const _Float16* hp = (t & 1) ? bufS : bufF;
            _Float16* hn = (t & 1) ? bufF : bufS;
            char* abuf = Als4[sub * 2 + (sc & 1)];
            ++sc;
            const unsigned g = gcur;

            POLL_OWN(g);
            STAGE(hp, abuf);
            sbar4(bar, lane, ++nb);   // tile ready (double-buffered: no 2nd join)

            // ---- decoder x (pipeline-local, all lanes) / encoder input prefetch ----
            float xr[8];
            float xv_pre[4];
            if (DEC) {
#pragma unroll
                for (int row = 0; row < 8; ++row) {
                    float p = 0.f;
                    if (t > 0) {
                        int xo = (row & 7) << 4;
                        f16x8 a0 = *(const f16x8*)(abuf + row * 2048 + ((lane * 32) ^ xo));
                        f16x8 a1 = *(const f16x8*)(abuf + row * 2048 + (((lane * 32) + 16) ^ xo));
#pragma unroll
                        for (int e = 0; e < 8; ++e)
                            p += (float)a0[e] * wout[e] + (float)a1[e] * wout[8 + e];
                        p += __shfl_xor(p, 1);  p += __shfl_xor(p, 2);
                        p += __shfl_xor(p, 4);  p += __shfl_xor(p, 8);
                        p += __shfl_xor(p, 16); p += __shfl_xor(p, 32);
                        p += bout_v;
                        if (jt == 0 && np == 0 && lane == row)
                            outp[(size_t)(b0s + row) * T + (t - 1)] = p;
                    }
                    xr[row] = (t > 0) ? p : 0.f;
                }
            } else {
                if (kg < 2) {
#pragma unroll
                    for (int reg = 0; reg < 4; ++reg)
                        xv_pre[reg] = input[(size_t)(b0s + kg * 4 + reg) * T + t];
                }
            }

            // ---- MFMA: 3 gates x full K (A rows mirrored: r16&7) ----
            f32x4 aR = {0.f, 0.f, 0.f, 0.f}, aZ = {0.f, 0.f, 0.f, 0.f},
                  aN = {0.f, 0.f, 0.f, 0.f};
            const int ar = r16 & 7;
#pragma unroll
            for (int i = 0; i < 32; ++i) {
                int kb = (i << 6) + (kg << 4);
                f16x8 a = *(const f16x8*)(abuf + (ar << 11) + (kb ^ (ar << 4)));
                aR = __builtin_amdgcn_mfma_f32_16x16x32_f16(a, wB[i], aR, 0, 0, 0);
                aZ = __builtin_amdgcn_mfma_f32_16x16x32_f16(a, wB[32 + i], aZ, 0, 0, 0);
                aN = __builtin_amdgcn_mfma_f32_16x16x32_f16(a, wB[64 + i], aN, 0, 0, 0);
            }

            // ---- epilogue (wave-local; C rows 0..7 = kg<2) ----
            if (kg < 2) {
#pragma unroll
                for (int reg = 0; reg < 4; ++reg) {
                    int row = kg * 4 + reg;
                    float xv = DEC ? (kg ? xr[4 + reg] : xr[reg]) : xv_pre[reg];
                    float r = sigmoidf_(xv * wi_r + bi_r + aR[reg] + bh_r);
                    float z = sigmoidf_(xv * wi_z + bi_z + aZ[reg] + bh_z);
                    float n = tanhf_(xv * wi_n + bi_n + r * (aN[reg] + bh_n));
                    float hNew = (1.f - z) * n + z * hreg[reg];
                    hreg[reg] = hNew;
                    hout[row][np * 16 + r16] = (_Float16)hNew;
                }
            }

            PUBLISH_OWN(hn, g + 1);
            ++gcur;
        }
    };

    // ---- encoder: h_init in A; ends with h_T in A (tag 513) ----
    phase(false, h16A, h16B, Wih_e, bih_e, bhh_e);

    // ---- bottleneck (pipeline-local): stage h_T, feats, h0 -> B (tag 514) ----
    {
        const unsigned g = gcur;   // 513
        char* abuf = Als4[sub * 2 + (sc & 1)];
        ++sc;
        POLL_OWN(g);
        STAGE(h16A, abuf);
        sbar4(bar, lane, ++nb);

        float ft[8][3];
#pragma unroll
        for (int c = 0; c < 3; ++c) {
            float we[16];
#pragma unroll
            for (int q = 0; q < 4; ++q) {
                f32x4 w4 = *(const f32x4*)(Wenc + c * H + lane * 16 + q * 4);
                we[q * 4 + 0] = w4[0]; we[q * 4 + 1] = w4[1];
                we[q * 4 + 2] = w4[2]; we[q * 4 + 3] = w4[3];
            }
#pragma unroll
            for (int row = 0; row < 8; ++row) {
                int xo = (row & 7) << 4;
                f16x8 a0 = *(const f16x8*)(abuf + row * 2048 + ((lane * 32) ^ xo));
                f16x8 a1 = *(const f16x8*)(abuf + row * 2048 + (((lane * 32) + 16) ^ xo));
                float p = 0.f;
#pragma unroll
                for (int e = 0; e < 8; ++e)
                    p += (float)a0[e] * we[e] + (float)a1[e] * we[8 + e];
                p += __shfl_xor(p, 1);  p += __shfl_xor(p, 2);
                p += __shfl_xor(p, 4);  p += __shfl_xor(p, 8);
                p += __shfl_xor(p, 16); p += __shfl_xor(p, 32);
                float f = sigmoidf_(p + benc[c]);
                ft[row][c] = f;
                if (jt == 0 && np == 0 && lane == row)
                    featOut[(b0s + row) * 3 + c] = f;
            }
        }
        if (kg < 2) {
#pragma unroll
            for (int reg = 0; reg < 4; ++reg) {
                int row = kg * 4 + reg;
                float f0 = kg ? ft[4 + reg][0] : ft[reg][0];
                float f1 = kg ? ft[4 + reg][1] : ft[reg][1];
                float f2 = kg ? ft[4 + reg][2] : ft[reg][2];
                float v = f0 * Wdec[j * 3 + 0] + f1 * Wdec[j * 3 + 1] +
                          f2 * Wdec[j * 3 + 2] + bdec[j];
                hreg[reg] = v;
                hout[row][np * 16 + r16] = (_Float16)v;
            }
        }
        PUBLISH_OWN(h16B, g + 1);
        ++gcur;   // 514
    }

    load_weights(wB, Whh_d, j, kg);
#pragma unroll
    for (int q = 0; q < 4; ++q) {
        f32x4 w4 = *(const f32x4*)(Wout + lane * 16 + q * 4);
        wout[q * 4 + 0] = w4[0]; wout[q * 4 + 1] = w4[1];
        wout[q * 4 + 2] = w4[2]; wout[q * 4 + 3] = w4[3];
    }

    // ---- decoder: h0 in B; ends with h_T' in B (tag 1026) ----
    phase(true, h16B, h16A, Wih_d, bih_d, bhh_d);

    // ---- final column: out[:, T-1] = h_T' . Wout + bout ----
    {
        const unsigned g = gcur;   // 1026
        char* abuf = Als4[sub * 2 + (sc & 1)];
        ++sc;
        POLL_OWN(g);
        STAGE(h16B, abuf);
        sbar4(bar, lane, ++nb);
        if (jt == 0 && np == 0) {
#pragma unroll
            for (int row = 0; row < 8; ++row) {
                int xo = (row & 7) << 4;
                f16x8 a0 = *(const f16x8*)(abuf + row * 2048 + ((lane * 32) ^ xo));
                f16x8 a1 = *(const f16x8*)(abuf + row * 2048 + (((lane * 32) + 16) ^ xo));
                float p = 0.f;
#pragma unroll
                for (int e = 0; e < 8; ++e)
                    p += (float)a0[e] * wout[e] + (float)a1[e] * wout[8 + e];
                p += __shfl_xor(p, 1);  p += __shfl_xor(p, 2);
                p += __shfl_xor(p, 4);  p += __shfl_xor(p, 8);
                p += __shfl_xor(p, 16); p += __shfl_xor(p, 32);
                if (lane == row)
                    outp[(size_t)(b0s + row) * T + (T - 1)] = p + bout_v;
            }
        }
    }
}

__global__ __launch_bounds__(256) void loss_partial(
    const float* __restrict__ input, const float* __restrict__ outp,
    float* __restrict__ partial)
{
    int idx = blockIdx.x * blockDim.x + threadIdx.x;
    float s = 0.f;
    for (int i = idx; i < B * T; i += gridDim.x * blockDim.x) {
        float d = input[i] - outp[i];
        s += d * d;
    }
#pragma unroll
    for (int off = 32; off; off >>= 1) s += __shfl_down(s, off);
    __shared__ float ws[4];
    if ((threadIdx.x & 63) == 0) ws[threadIdx.x >> 6] = s;
    __syncthreads();
    if (threadIdx.x == 0) partial[blockIdx.x] = ws[0] + ws[1] + ws[2] + ws[3];
}

__global__ __launch_bounds__(256) void loss_final(
    const float* __restrict__ partial, float* __restrict__ loss)
{
    int tid = threadIdx.x;
    float s = partial[tid];
#pragma unroll
    for (int off = 32; off; off >>= 1) s += __shfl_down(s, off);
    __shared__ float ws[4];
    if ((tid & 63) == 0) ws[tid >> 6] = s;
    __syncthreads();
    if (tid == 0) loss[0] = (ws[0] + ws[1] + ws[2] + ws[3]) * (1.0f / (float)(B * T));
}

extern "C" void kernel_launch(void* const* d_in, const int* in_sizes, int n_in,
                              void* d_out, int out_size, void* d_ws, size_t ws_size,
                              hipStream_t stream) {
    const float* input = (const float*)d_in[0];
    const float* h_init = (const float*)d_in[1];
    const float* Wih_e = (const float*)d_in[2];
    const float* Whh_e = (const float*)d_in[3];
    const float* bih_e = (const float*)d_in[4];
    const float* bhh_e = (const float*)d_in[5];
    const float* Wenc  = (const float*)d_in[6];
    const float* benc  = (const float*)d_in[7];
    const float* Wdec  = (const float*)d_in[8];
    const float* bdec  = (const float*)d_in[9];
    const float* Wih_d = (const float*)d_in[10];
    const float* Whh_d = (const float*)d_in[11];
    const float* bih_d = (const float*)d_in[12];
    const float* bhh_d = (const float*)d_in[13];
    const float* Wout  = (const float*)d_in[14];
    const float* bout  = (const float*)d_in[15];
    (void)in_sizes; (void)n_in; (void)out_size; (void)ws_size;

    float* out = (float*)d_out;
    float* lossp = out;                    // [1]
    float* feat = out + 1;                 // [B*3]
    float* outp = out + 1 + B * 3;         // [B*T]

    // ---- workspace layout ----
    char* ws = (char*)d_ws;
    _Float16* h16A = (_Float16*)ws;                  ws += (size_t)B * H * 2;
    _Float16* h16B = (_Float16*)ws;                  ws += (size_t)B * H * 2;
    float* partial = (float*)ws;                     ws += 256 * 4;
    ws = (char*)(((uintptr_t)ws + 127) & ~(uintptr_t)127);
    unsigned* tags = (unsigned*)ws;                  ws += (size_t)32 * 1024 * 4;  // [bt*2+sub][64 tags x16]

    // tags must start at 0 every call (ws poisoned once, not restored)
    hipMemsetAsync(tags, 0, (size_t)32 * 1024 * 4, stream);

    gru_persistent<<<dim3(NBLK), dim3(512), 0, stream>>>(
        input, h_init, Wih_e, Whh_e, bih_e, bhh_e, Wenc, benc, Wdec, bdec,
        Wih_d, Whh_d, bih_d, bhh_d, Wout, bout,
        feat, outp, h16A, h16B, tags);

    loss_partial<<<256, 256, 0, stream>>>(input, outp, partial);
    loss_final<<<1, 256, 0, stream>>>(partial, lossp);
}

// Round 17
// 7197.321 us; speedup vs baseline: 4.4923x; 4.2912x over previous
//
#include <hip/hip_runtime.h>
#include <math.h>

#define B 256
#define T 512
#define H 1024
#define NBLK 256

typedef _Float16 f16x8 __attribute__((ext_vector_type(8)));
typedef float f32x4 __attribute__((ext_vector_type(4)));
typedef unsigned u32x4 __attribute__((ext_vector_type(4)));

__device__ __forceinline__ float sigmoidf_(float x) { return 1.0f / (1.0f + __expf(-x)); }
__device__ __forceinline__ float tanhf_(float x) {
    float ax = fabsf(x);
    float t = __expf(-2.0f * ax);
    float r = (1.0f - t) / (1.0f + t);
    return x < 0.f ? -r : r;
}

// ---- agent-coherent access (write-through LLC, bypass L1/L2; no fences) ----
__device__ __forceinline__ void store_b128_coh(void* p, u32x4 v) {
    asm volatile("global_store_dwordx4 %0, %1, off sc0 sc1" :: "v"(p), "v"(v) : "memory");
}
__device__ __forceinline__ u32x4 load_b16_coh(const void* p) {
    u32x4 v;
    asm volatile("global_load_dwordx4 %0, %1, off sc0 sc1" : "=v"(v) : "v"(p));
    return v;
}
__device__ __forceinline__ f32x4 load_f128_coh(const void* p) {
    f32x4 v;
    asm volatile("global_load_dwordx4 %0, %1, off sc0 sc1" : "=v"(v) : "v"(p));
    return v;
}
__device__ __forceinline__ void storef_coh(float* p, float v) {
    __hip_atomic_store(p, v, __ATOMIC_RELAXED, __HIP_MEMORY_SCOPE_AGENT);
}
__device__ __forceinline__ float loadf_coh(const float* p) {
    return __hip_atomic_load((float*)p, __ATOMIC_RELAXED, __HIP_MEMORY_SCOPE_AGENT);
}
__device__ __forceinline__ unsigned load_tag(const unsigned* p) {
    return __hip_atomic_load((unsigned*)p, __ATOMIC_RELAXED, __HIP_MEMORY_SCOPE_AGENT);
}
__device__ __forceinline__ void store_tag(unsigned* p, unsigned v) {
    __hip_atomic_store(p, v, __ATOMIC_RELAXED, __HIP_MEMORY_SCOPE_AGENT);
}

// Load this wave's 48 B-fragments (3 gates x 16 k-chunks of its K-half),
// f32 -> f16. j = this lane's B row; one-time cost (lives in AGPRs).
__device__ __forceinline__ void load_weights(f16x8 (&wB)[48], const float* __restrict__ W,
                                             int j, int kh, int kg) {
#pragma unroll
    for (int g = 0; g < 3; ++g)
#pragma unroll
        for (int i = 0; i < 16; ++i) {
            const float* p = W + (((size_t)g << 10) + j) * 1024 + (kh << 9) + (i << 5) + (kg << 3);
            float4 u = *(const float4*)p;
            float4 v = *(const float4*)(p + 4);
            f16x8 o;
            o[0] = (_Float16)u.x; o[1] = (_Float16)u.y; o[2] = (_Float16)u.z; o[3] = (_Float16)u.w;
            o[4] = (_Float16)v.x; o[5] = (_Float16)v.y; o[6] = (_Float16)v.z; o[7] = (_Float16)v.w;
            wB[g * 16 + i] = o;
        }
}

// Decentralized stripe publish (kh0 wave np): pack own 16x16 f16 stripe from
// hout (wave-local LDS round-trip), 32 coalesced 16B stores, drain, own tag.
#define PUBLISH_STRIPE(HN, G)                                                            \
    do {                                                                                 \
        if (lane < 32) {                                                                 \
            int prow = lane >> 1, pch = lane & 1;                                        \
            u32x4 pv = *(const u32x4*)((const char*)&hout[0][0] +                        \
                                       prow * 128 + np * 32 + pch * 16);                 \
            store_b128_coh((HN) + ((size_t)(b0 + prow) << 10) + j0 + np * 16 + pch * 8,  \
                           pv);                                                          \
        }                                                                                \
        asm volatile("s_waitcnt vmcnt(0)" ::: "memory");                                 \
        if (lane == 0) store_tag(gtags + (jt * 4 + np) * 16, (G));                       \
    } while (0)

// One GRU phase: T steps. Weights in wB (AGPRs), h f32 master in hreg.
// h16 [B][H] ping-pong: step t reads buf[t&1], writes buf[(t+1)&1].
// Per step: wave1 polls 64 tags -> join -> stage (+vectorized x-gather by
// wave0) -> join -> MFMA -> join -> kh0 epilogue + parallel stripe publish.
template <bool DEC>
__device__ __forceinline__ void run_phase(
    int b0, int j0, int bt, int jt, int j, int np, int kh, int kg, int r16,
    int tid, int lane, int wv,
    const f16x8 (&wB)[48], float (&hreg)[4],
    _Float16* __restrict__ h16A, _Float16* __restrict__ h16B,
    const float* __restrict__ Wih, const float* __restrict__ bih,
    const float* __restrict__ bhh,
    const float* __restrict__ input, const float* __restrict__ Wout, float bout_v,
    float* __restrict__ xpart, float* __restrict__ outp,
    unsigned* gtags, unsigned& gcur,
    char* Als, f32x4 (*red)[3][64], _Float16 (*hout)[64], float* xv_s)
{
    const float wi_r = Wih[j], wi_z = Wih[H + j], wi_n = Wih[2 * H + j];
    const float bi_r = bih[j], bi_z = bih[H + j], bi_n = bih[2 * H + j];
    const float bh_r = bhh[j], bh_z = bhh[H + j], bh_n = bhh[2 * H + j];
    const float wo = DEC ? Wout[j] : 0.f;
    const int kc = tid & 127, rb = tid >> 7;

    for (int t = 0; t < T; ++t) {
        const _Float16* hp = (t & 1) ? h16B : h16A;
        _Float16* hn = (t & 1) ? h16A : h16B;

        // ---- poll (wave 1, 64 lanes x 64 tags) + release ----
        if (wv == 1) {
            while (load_tag(gtags + lane * 16) < gcur) __builtin_amdgcn_s_sleep(1);
        }
        __builtin_amdgcn_sched_barrier(0);
        __syncthreads();

        // ---- stage 16x1024 tile + vectorized x-gather (wave 0) ----
        u32x4 tmp[4];
#pragma unroll
        for (int i = 0; i < 4; ++i) {
            int row = i * 4 + rb;
            tmp[i] = load_b16_coh(hp + ((size_t)(b0 + row) << 10) + (kc << 3));
        }
        f32x4 x0 = {0.f, 0.f, 0.f, 0.f}, x1 = x0, x2 = x0, x3 = x0;
        if (DEC && wv == 0 && t > 0) {
            const float* xp = xpart + ((t - 1) & 1) * 16384 +
                              (size_t)(b0 + (lane >> 2)) * 64 + (lane & 3) * 16;
            x0 = load_f128_coh(xp);
            x1 = load_f128_coh(xp + 4);
            x2 = load_f128_coh(xp + 8);
            x3 = load_f128_coh(xp + 12);
        }
        asm volatile("s_waitcnt vmcnt(0)" ::: "memory");
        __builtin_amdgcn_sched_barrier(0);
        if (DEC && wv == 0) {
            float s = x0[0] + x0[1] + x0[2] + x0[3] + x1[0] + x1[1] + x1[2] + x1[3] +
                      x2[0] + x2[1] + x2[2] + x2[3] + x3[0] + x3[1] + x3[2] + x3[3];
            s += __shfl_xor(s, 1);
            s += __shfl_xor(s, 2);
            if ((lane & 3) == 0) {
                int row = lane >> 2;
                float xv = (t > 0) ? (s + bout_v) : 0.f;
                xv_s[row] = xv;
                if (t > 0 && jt == 0) outp[(size_t)(b0 + row) * T + (t - 1)] = xv;
            }
        }
#pragma unroll
        for (int i = 0; i < 4; ++i) {
            int row = i * 4 + rb;
            *(u32x4*)(Als + row * 2048 + ((kc << 4) ^ ((row & 7) << 4))) = tmp[i];
        }
        __syncthreads();

        // ---- MFMA: 3 gates x K-half ----
        f32x4 aR = {0.f, 0.f, 0.f, 0.f}, aZ = {0.f, 0.f, 0.f, 0.f}, aN = {0.f, 0.f, 0.f, 0.f};
#pragma unroll
        for (int i = 0; i < 16; ++i) {
            int kb = (kh << 10) + (i << 6) + (kg << 4);
            f16x8 a = *(const f16x8*)(Als + (r16 << 11) + (kb ^ ((r16 & 7) << 4)));
            aR = __builtin_amdgcn_mfma_f32_16x16x32_f16(a, wB[i], aR, 0, 0, 0);
            aZ = __builtin_amdgcn_mfma_f32_16x16x32_f16(a, wB[16 + i], aZ, 0, 0, 0);
            aN = __builtin_amdgcn_mfma_f32_16x16x32_f16(a, wB[32 + i], aN, 0, 0, 0);
        }
        if (kh == 1) {
            red[np][0][lane] = aR; red[np][1][lane] = aZ; red[np][2][lane] = aN;
        }
        __syncthreads();

        // ---- epilogue + decentralized publish (kh0 waves) ----
        if (kh == 0) {
            f32x4 rR = red[np][0][lane], rZ = red[np][1][lane], rN = red[np][2][lane];
#pragma unroll
            for (int reg = 0; reg < 4; ++reg) {
                int row = kg * 4 + reg;
                int b = b0 + row;
                float xv = DEC ? xv_s[row] : input[(size_t)b * T + t];
                float r = sigmoidf_(xv * wi_r + bi_r + aR[reg] + rR[reg] + bh_r);
                float z = sigmoidf_(xv * wi_z + bi_z + aZ[reg] + rZ[reg] + bh_z);
                float n = tanhf_(xv * wi_n + bi_n + r * (aN[reg] + rN[reg] + bh_n));
                float hNew = (1.f - z) * n + z * hreg[reg];
                hreg[reg] = hNew;
                hout[row][np * 16 + r16] = (_Float16)hNew;
                if (DEC) {
                    float v = hNew * wo;
                    v += __shfl_xor(v, 1); v += __shfl_xor(v, 2);
                    v += __shfl_xor(v, 4); v += __shfl_xor(v, 8);
                    if (r16 == 0)
                        storef_coh(xpart + (t & 1) * 16384 + (size_t)b * 64 + jt * 4 + np, v);
                }
            }
            PUBLISH_STRIPE(hn, gcur + 1);
        }
        ++gcur;
    }
}

__global__ __launch_bounds__(512, 2) void gru_persistent(
    const float* __restrict__ input, const float* __restrict__ h_init,
    const float* __restrict__ Wih_e, const float* __restrict__ Whh_e,
    const float* __restrict__ bih_e, const float* __restrict__ bhh_e,
    const float* __restrict__ Wenc, const float* __restrict__ benc,
    const float* __restrict__ Wdec, const float* __restrict__ bdec,
    const float* __restrict__ Wih_d, const float* __restrict__ Whh_d,
    const float* __restrict__ bih_d, const float* __restrict__ bhh_d,
    const float* __restrict__ Wout, const float* __restrict__ boutp,
    float* __restrict__ featOut, float* __restrict__ outp,
    _Float16* __restrict__ h16A, _Float16* __restrict__ h16B,
    float* __restrict__ xpart, float* __restrict__ fpart,
    unsigned* tags)
{
    __shared__ __align__(16) char Als[32768];
    __shared__ f32x4 red[4][3][64];
    __shared__ __align__(16) _Float16 hout[16][64];
    __shared__ float xv_s[16];
    __shared__ float fp_np[4][16][3];
    __shared__ float feats[16][3];

    const int tid = threadIdx.x;
    const int lane = tid & 63;
    const int wv = tid >> 6;     // 0..7
    const int kh = wv & 1;       // K-half
    const int np = wv >> 1;      // n-quadrant 0..3
    const int kg = lane >> 4;    // 0..3
    const int r16 = lane & 15;
    const int bid = blockIdx.x;
    const int bt = bid & 15, jt = bid >> 4;   // group = {bt, bt+16, ...}
    const int b0 = bt * 16, j0 = jt * 64;
    const int j = j0 + np * 16 + r16;
    const float bout_v = boutp[0];
    unsigned* gtags = tags + (size_t)bt * 1024;  // 64 tags x 16-dword stride
    unsigned gcur = 0;

    f16x8 wB[48];
    float hreg[4] = {0.f, 0.f, 0.f, 0.f};

    // ---- init: hreg + publish h_init stripes to h16A (tag 1) ----
    if (kh == 0) {
#pragma unroll
        for (int reg = 0; reg < 4; ++reg) {
            int row = kg * 4 + reg;
            float v = h_init[((size_t)(b0 + row) << 10) + j];
            hreg[reg] = v;
            hout[row][np * 16 + r16] = (_Float16)v;
        }
        PUBLISH_STRIPE(h16A, 1u);
    }
    gcur = 1;
    load_weights(wB, Whh_e, j, kh, kg);

    // ---- encoder: 512 steps (polls 1..512, publishes 2..513) ----
    run_phase<false>(b0, j0, bt, jt, j, np, kh, kg, r16, tid, lane, wv, wB, hreg,
                     h16A, h16B, Wih_e, bih_e, bhh_e, input, Wout, bout_v,
                     xpart, outp, gtags, gcur, Als, red, hout, xv_s);
    // gcur = 513; h_T stripes in h16A

    // ---- bottleneck: features (16-way j reduction via fpart) + h0 ----
    {
        float we0 = Wenc[j], we1 = Wenc[H + j], we2 = Wenc[2 * H + j];
        if (kh == 0) {
#pragma unroll
            for (int reg = 0; reg < 4; ++reg) {
                float h = hreg[reg];
                float q0 = h * we0, q1 = h * we1, q2 = h * we2;
#pragma unroll
                for (int m = 1; m < 16; m <<= 1) {
                    q0 += __shfl_xor(q0, m);
                    q1 += __shfl_xor(q1, m);
                    q2 += __shfl_xor(q2, m);
                }
                if (r16 == 0) {
                    fp_np[np][kg * 4 + reg][0] = q0;
                    fp_np[np][kg * 4 + reg][1] = q1;
                    fp_np[np][kg * 4 + reg][2] = q2;
                }
            }
        }
        __syncthreads();
        if (tid < 48) {
            int bi = tid / 3, c = tid % 3;
            float s = fp_np[0][bi][c] + fp_np[1][bi][c] + fp_np[2][bi][c] + fp_np[3][bi][c];
            storef_coh(fpart + (size_t)(b0 + bi) * 48 + jt * 3 + c, s);
        }
        if (wv == 0) {   // fpart stores were all by wave 0 (tid<48)
            asm volatile("s_waitcnt vmcnt(0)" ::: "memory");
            if (lane < 4) store_tag(gtags + (jt * 4 + lane) * 16, gcur + 1);
        }
        if (wv == 1) {
            while (load_tag(gtags + lane * 16) < gcur + 1) __builtin_amdgcn_s_sleep(1);
        }
        __builtin_amdgcn_sched_barrier(0);
        __syncthreads();

        if (tid < 48) {
            int bi = tid / 3, c = tid % 3;
            float s = 0.f;
            const float* fp = fpart + (size_t)(b0 + bi) * 48 + c;
#pragma unroll
            for (int q = 0; q < 16; ++q) s += loadf_coh(fp + q * 3);
            float f = sigmoidf_(s + benc[c]);
            feats[bi][c] = f;
            if (jt == 0) featOut[(b0 + bi) * 3 + c] = f;
        }
        __syncthreads();

        // h0 = feats @ Wdec.T + bdec -> hreg + publish stripes to h16A (tag gcur+2)
        if (kh == 0) {
#pragma unroll
            for (int reg = 0; reg < 4; ++reg) {
                int row = kg * 4 + reg;
                float v = feats[row][0] * Wdec[j * 3 + 0] + feats[row][1] * Wdec[j * 3 + 1] +
                          feats[row][2] * Wdec[j * 3 + 2] + bdec[j];
                hreg[reg] = v;
                hout[row][np * 16 + r16] = (_Float16)v;
            }
            PUBLISH_STRIPE(h16A, gcur + 2);
        }
        gcur += 2;   // = 515
    }
    load_weights(wB, Whh_d, j, kh, kg);

    // ---- decoder: 512 steps (polls 515..1026, publishes 516..1027) ----
    run_phase<true>(b0, j0, bt, jt, j, np, kh, kg, r16, tid, lane, wv, wB, hreg,
                    h16A, h16B, Wih_d, bih_d, bhh_d, input, Wout, bout_v,
                    xpart, outp, gtags, gcur, Als, red, hout, xv_s);
    // gcur = 1027

    // ---- final output column: poll last publishes, gather xpart slot 1 ----
    if (wv == 1) {
        while (load_tag(gtags + lane * 16) < gcur) __builtin_amdgcn_s_sleep(1);
    }
    __builtin_amdgcn_sched_barrier(0);
    __syncthreads();
    if (jt == 0 && wv == 0) {
        const float* xp = xpart + 16384 +
                          (size_t)(b0 + (lane >> 2)) * 64 + (lane & 3) * 16;
        f32x4 x0 = load_f128_coh(xp);
        f32x4 x1 = load_f128_coh(xp + 4);
        f32x4 x2 = load_f128_coh(xp + 8);
        f32x4 x3 = load_f128_coh(xp + 12);
        asm volatile("s_waitcnt vmcnt(0)" ::: "memory");
        __builtin_amdgcn_sched_barrier(0);
        float s = x0[0] + x0[1] + x0[2] + x0[3] + x1[0] + x1[1] + x1[2] + x1[3] +
                  x2[0] + x2[1] + x2[2] + x2[3] + x3[0] + x3[1] + x3[2] + x3[3];
        s += __shfl_xor(s, 1);
        s += __shfl_xor(s, 2);
        if ((lane & 3) == 0)
            outp[(size_t)(b0 + (lane >> 2)) * T + (T - 1)] = s + bout_v;
    }
}

__global__ __launch_bounds__(256) void loss_partial(
    const float* __restrict__ input, const float* __restrict__ outp,
    float* __restrict__ partial)
{
    int idx = blockIdx.x * blockDim.x + threadIdx.x;
    float s = 0.f;
    for (int i = idx; i < B * T; i += gridDim.x * blockDim.x) {
        float d = input[i] - outp[i];
        s += d * d;
    }
#pragma unroll
    for (int off = 32; off; off >>= 1) s += __shfl_down(s, off);
    __shared__ float ws[4];
    if ((threadIdx.x & 63) == 0) ws[threadIdx.x >> 6] = s;
    __syncthreads();
    if (threadIdx.x == 0) partial[blockIdx.x] = ws[0] + ws[1] + ws[2] + ws[3];
}

__global__ __launch_bounds__(256) void loss_final(
    const float* __restrict__ partial, float* __restrict__ loss)
{
    int tid = threadIdx.x;
    float s = partial[tid];
#pragma unroll
    for (int off = 32; off; off >>= 1) s += __shfl_down(s, off);
    __shared__ float ws[4];
    if ((tid & 63) == 0) ws[tid >> 6] = s;
    __syncthreads();
    if (tid == 0) loss[0] = (ws[0] + ws[1] + ws[2] + ws[3]) * (1.0f / (float)(B * T));
}

extern "C" void kernel_launch(void* const* d_in, const int* in_sizes, int n_in,
                              void* d_out, int out_size, void* d_ws, size_t ws_size,
                              hipStream_t stream) {
    const float* input = (const float*)d_in[0];
    const float* h_init = (const float*)d_in[1];
    const float* Wih_e = (const float*)d_in[2];
    const float* Whh_e = (const float*)d_in[3];
    const float* bih_e = (const float*)d_in[4];
    const float* bhh_e = (const float*)d_in[5];
    const float* Wenc  = (const float*)d_in[6];
    const float* benc  = (const float*)d_in[7];
    const float* Wdec  = (const float*)d_in[8];
    const float* bdec  = (const float*)d_in[9];
    const float* Wih_d = (const float*)d_in[10];
    const float* Whh_d = (const float*)d_in[11];
    const float* bih_d = (const float*)d_in[12];
    const float* bhh_d = (const float*)d_in[13];
    const float* Wout  = (const float*)d_in[14];
    const float* bout  = (const float*)d_in[15];
    (void)in_sizes; (void)n_in; (void)out_size; (void)ws_size;

    float* out = (float*)d_out;
    float* lossp = out;                    // [1]
    float* feat = out + 1;                 // [B*3]
    float* outp = out + 1 + B * 3;         // [B*T]

    // ---- workspace layout ----
    char* ws = (char*)d_ws;
    _Float16* h16A = (_Float16*)ws;                  ws += (size_t)B * H * 2;
    _Float16* h16B = (_Float16*)ws;                  ws += (size_t)B * H * 2;
    float* xpart = (float*)ws;                       ws += 2 * 16384 * 4;  // [2][256][64]
    float* fpart = (float*)ws;                       ws += (size_t)B * 48 * 4;
    float* partial = (float*)ws;                     ws += 256 * 4;
    ws = (char*)(((uintptr_t)ws + 127) & ~(uintptr_t)127);
    unsigned* tags = (unsigned*)ws;                  ws += 16 * 1024 * 4;  // [bt][64 tags x16]

    // tags must start at 0 every call (ws poisoned once, not restored)
    hipMemsetAsync(tags, 0, 16 * 1024 * 4, stream);

    gru_persistent<<<dim3(NBLK), dim3(512), 0, stream>>>(
        input, h_init, Wih_e, Whh_e, bih_e, bhh_e, Wenc, benc, Wdec, bdec,
        Wih_d, Whh_d, bih_d, bhh_d, Wout, bout,
        feat, outp, h16A, h16B, xpart, fpart, tags);

    loss_partial<<<256, 256, 0, stream>>>(input, outp, partial);
    loss_final<<<1, 256, 0, stream>>>(partial, lossp);
}

// Round 18
// 5966.302 us; speedup vs baseline: 5.4192x; 1.2063x over previous
//
#include <hip/hip_runtime.h>
#include <math.h>

#define B 256
#define T 512
#define H 1024
#define NBLK 256

typedef _Float16 f16x8 __attribute__((ext_vector_type(8)));
typedef float f32x4 __attribute__((ext_vector_type(4)));
typedef unsigned u32x4 __attribute__((ext_vector_type(4)));

__device__ __forceinline__ float sigmoidf_(float x) { return 1.0f / (1.0f + __expf(-x)); }
__device__ __forceinline__ float tanhf_(float x) {
    float ax = fabsf(x);
    float t = __expf(-2.0f * ax);
    float r = (1.0f - t) / (1.0f + t);
    return x < 0.f ? -r : r;
}

// ---- agent-coherent access (write-through LLC, bypass L1/L2; no fences) ----
__device__ __forceinline__ void store_b128_coh(void* p, u32x4 v) {
    asm volatile("global_store_dwordx4 %0, %1, off sc0 sc1" :: "v"(p), "v"(v) : "memory");
}
__device__ __forceinline__ u32x4 load_b16_coh(const void* p) {
    u32x4 v;
    asm volatile("global_load_dwordx4 %0, %1, off sc0 sc1" : "=v"(v) : "v"(p));
    return v;
}
__device__ __forceinline__ void storef_coh(float* p, float v) {
    __hip_atomic_store(p, v, __ATOMIC_RELAXED, __HIP_MEMORY_SCOPE_AGENT);
}
__device__ __forceinline__ float loadf_coh(const float* p) {
    return __hip_atomic_load((float*)p, __ATOMIC_RELAXED, __HIP_MEMORY_SCOPE_AGENT);
}

// Load this wave's 48 B-fragments (3 gates x 16 k-chunks of its K-half),
// f32 -> f16. j = this lane's B row; one-time cost (lives in AGPRs).
__device__ __forceinline__ void load_weights(f16x8 (&wB)[48], const float* __restrict__ W,
                                             int j, int kh, int kg) {
#pragma unroll
    for (int g = 0; g < 3; ++g)
#pragma unroll
        for (int i = 0; i < 16; ++i) {
            const float* p = W + (((size_t)g << 10) + j) * 1024 + (kh << 9) + (i << 5) + (kg << 3);
            float4 u = *(const float4*)p;
            float4 v = *(const float4*)(p + 4);
            f16x8 o;
            o[0] = (_Float16)u.x; o[1] = (_Float16)u.y; o[2] = (_Float16)u.z; o[3] = (_Float16)u.w;
            o[4] = (_Float16)v.x; o[5] = (_Float16)v.y; o[6] = (_Float16)v.z; o[7] = (_Float16)v.w;
            wB[g * 16 + i] = o;
        }
}

// ---- publish + sync tail ----
// wave0: 128 coalesced 16B scoped stores of hout -> hn slice, vmcnt(0) drain,
//        tid0 stores tag = gcur+1.
// wave2 lanes 0..15: poll all 16 group tags >= gcur+1 (overlaps wave0 drain).
// __syncthreads joins. Monotone tags, no reset race.
#define PUBLISH_SYNC(hn_expr, EXTRA_STORES)                                              \
    do {                                                                                 \
        if (tid < 64) {                                                                  \
            _Float16* hn_ = (hn_expr);                                                   \
            int ch0 = tid, ch1 = tid + 64;                                               \
            store_b128_coh(hn_ + ((size_t)(b0 + (ch0 >> 3)) << 10) + j0 + (ch0 & 7) * 8, \
                           *(const u32x4*)&hout[ch0 >> 3][(ch0 & 7) * 8]);               \
            store_b128_coh(hn_ + ((size_t)(b0 + (ch1 >> 3)) << 10) + j0 + (ch1 & 7) * 8, \
                           *(const u32x4*)&hout[ch1 >> 3][(ch1 & 7) * 8]);               \
        }                                                                                \
        EXTRA_STORES                                                                     \
        if (tid >= 128 && tid < 144) {                                                   \
            unsigned tgt = gcur + 1;                                                     \
            while (__hip_atomic_load(&tags[(bt * 16 + (tid - 128)) * 32],                \
                                     __ATOMIC_RELAXED, __HIP_MEMORY_SCOPE_AGENT) < tgt)  \
                __builtin_amdgcn_s_sleep(1);                                             \
        }                                                                                \
        if (tid < 64) {                                                                  \
            asm volatile("s_waitcnt vmcnt(0)" ::: "memory");                             \
            if (tid == 0)                                                                \
                __hip_atomic_store(&tags[(bt * 16 + jt) * 32], gcur + 1,                 \
                                   __ATOMIC_RELAXED, __HIP_MEMORY_SCOPE_AGENT);          \
        }                                                                                \
        __syncthreads();                                                                 \
        ++gcur;                                                                          \
    } while (0)

// One GRU phase: T steps. Weights in wB (AGPRs), h f32 master in hreg.
// h16 full-matrix [B][H] ping-pong: step t reads buf[t&1], writes buf[(t+1)&1].
template <bool DEC>
__device__ __forceinline__ void run_phase(
    int b0, int j0, int bt, int jt, int j, int np, int kh, int kg, int r16,
    int tid, int lane,
    const f16x8 (&wB)[48], float (&hreg)[4],
    _Float16* __restrict__ h16A, _Float16* __restrict__ h16B,
    const float* __restrict__ Wih, const float* __restrict__ bih,
    const float* __restrict__ bhh,
    const float* __restrict__ input, const float* __restrict__ Wout, float bout_v,
    float* __restrict__ xpart, float* __restrict__ outp,
    unsigned* tags, unsigned& gcur,
    char* Als, f32x4 (*red)[3][64], _Float16 (*hout)[64], float* xv_s, float (*xnp)[16])
{
    const float wi_r = Wih[j], wi_z = Wih[H + j], wi_n = Wih[2 * H + j];
    const float bi_r = bih[j], bi_z = bih[H + j], bi_n = bih[2 * H + j];
    const float bh_r = bhh[j], bh_z = bhh[H + j], bh_n = bhh[2 * H + j];
    const float wo = DEC ? Wout[j] : 0.f;
    const int kc = tid & 127, rb = tid >> 7;

    for (int t = 0; t < T; ++t) {
        const _Float16* hp = (t & 1) ? h16B : h16A;
        _Float16* hn = (t & 1) ? h16A : h16B;

        // ---- stage loads (freshness guaranteed by previous step's poll) ----
        u32x4 tmp[4];
#pragma unroll
        for (int i = 0; i < 4; ++i) {
            int row = i * 4 + rb;
            tmp[i] = load_b16_coh(hp + ((size_t)(b0 + row) << 10) + (kc << 3));
        }
        float xg = 0.f;
        if (DEC && t > 0 && tid < 16) {
            const float* xp = xpart + ((t - 1) & 1) * 4096 + (size_t)(b0 + tid) * 16;
#pragma unroll
            for (int q = 0; q < 16; ++q) xg += loadf_coh(xp + q);
            xg += bout_v;
        }
        asm volatile("s_waitcnt vmcnt(0)" ::: "memory");
        if (DEC && tid < 16) {
            float xv = (t > 0) ? xg : 0.f;
            xv_s[tid] = xv;
            if (t > 0 && jt == 0) outp[(size_t)(b0 + tid) * T + (t - 1)] = xv;
        }
#pragma unroll
        for (int i = 0; i < 4; ++i) {
            int row = i * 4 + rb;
            *(u32x4*)(Als + row * 2048 + ((kc << 4) ^ ((row & 7) << 4))) = tmp[i];
        }
        __syncthreads();

        // ---- MFMA: 3 gates x K-half ----
        f32x4 aR = {0.f, 0.f, 0.f, 0.f}, aZ = {0.f, 0.f, 0.f, 0.f}, aN = {0.f, 0.f, 0.f, 0.f};
#pragma unroll
        for (int i = 0; i < 16; ++i) {
            int kb = (kh << 10) + (i << 6) + (kg << 4);
            f16x8 a = *(const f16x8*)(Als + (r16 << 11) + (kb ^ ((r16 & 7) << 4)));
            aR = __builtin_amdgcn_mfma_f32_16x16x32_f16(a, wB[i], aR, 0, 0, 0);
            aZ = __builtin_amdgcn_mfma_f32_16x16x32_f16(a, wB[16 + i], aZ, 0, 0, 0);
            aN = __builtin_amdgcn_mfma_f32_16x16x32_f16(a, wB[32 + i], aN, 0, 0, 0);
        }
        if (kh == 1) {
            red[np][0][lane] = aR; red[np][1][lane] = aZ; red[np][2][lane] = aN;
        }
        __syncthreads();

        // ---- epilogue: K-reduce + GRU cell -> hout (LDS), xw -> xnp ----
        if (kh == 0) {
            f32x4 rR = red[np][0][lane], rZ = red[np][1][lane], rN = red[np][2][lane];
#pragma unroll
            for (int reg = 0; reg < 4; ++reg) {
                int row = kg * 4 + reg;
                int b = b0 + row;
                float xv = DEC ? xv_s[row] : input[(size_t)b * T + t];
                float r = sigmoidf_(xv * wi_r + bi_r + aR[reg] + rR[reg] + bh_r);
                float z = sigmoidf_(xv * wi_z + bi_z + aZ[reg] + rZ[reg] + bh_z);
                float n = tanhf_(xv * wi_n + bi_n + r * (aN[reg] + rN[reg] + bh_n));
                float hNew = (1.f - z) * n + z * hreg[reg];
                hreg[reg] = hNew;
                hout[row][np * 16 + r16] = (_Float16)hNew;
                if (DEC) {
                    float v = hNew * wo;
                    v += __shfl_xor(v, 1); v += __shfl_xor(v, 2);
                    v += __shfl_xor(v, 4); v += __shfl_xor(v, 8);
                    if (r16 == 0) xnp[np][row] = v;
                }
            }
        }
        __syncthreads();

        // ---- publish h_{t+1} (+ xpart), poll peers, join ----
        PUBLISH_SYNC(hn,
            if (DEC && tid < 16) {
                float s_ = xnp[0][tid] + xnp[1][tid] + xnp[2][tid] + xnp[3][tid];
                storef_coh(xpart + (t & 1) * 4096 + (size_t)(b0 + tid) * 16 + jt, s_);
            }
        );
    }
}

__global__ __launch_bounds__(512, 2) void gru_persistent(
    const float* __restrict__ input, const float* __restrict__ h_init,
    const float* __restrict__ Wih_e, const float* __restrict__ Whh_e,
    const float* __restrict__ bih_e, const float* __restrict__ bhh_e,
    const float* __restrict__ Wenc, const float* __restrict__ benc,
    const float* __restrict__ Wdec, const float* __restrict__ bdec,
    const float* __restrict__ Wih_d, const float* __restrict__ Whh_d,
    const float* __restrict__ bih_d, const float* __restrict__ bhh_d,
    const float* __restrict__ Wout, const float* __restrict__ boutp,
    float* __restrict__ featOut, float* __restrict__ outp,
    _Float16* __restrict__ h16A, _Float16* __restrict__ h16B,
    float* __restrict__ xpart, float* __restrict__ fpart,
    unsigned* tags)
{
    __shared__ __align__(16) char Als[32768];
    __shared__ f32x4 red[4][3][64];
    __shared__ __align__(16) _Float16 hout[16][64];
    __shared__ float xv_s[16];
    __shared__ float xnp[4][16];
    __shared__ float fp_np[4][16][3];
    __shared__ float feats[16][3];

    const int tid = threadIdx.x;
    const int lane = tid & 63;
    const int wv = tid >> 6;     // 0..7
    const int kh = wv & 1;       // K-half
    const int np = wv >> 1;      // n-quadrant 0..3
    const int kg = lane >> 4;    // 0..3
    const int r16 = lane & 15;
    const int bid = blockIdx.x;
    const int bt = bid & 15, jt = bid >> 4;   // group = {bt, bt+16, ...}
    const int b0 = bt * 16, j0 = jt * 64;
    const int j = j0 + np * 16 + r16;
    const float bout_v = boutp[0];
    unsigned gcur = 0;

    f16x8 wB[48];
    float hreg[4] = {0.f, 0.f, 0.f, 0.f};

    // ---- init: hreg + publish h_init slice to h16A (par0) ----
    if (kh == 0) {
#pragma unroll
        for (int reg = 0; reg < 4; ++reg) {
            int row = kg * 4 + reg;
            float v = h_init[((size_t)(b0 + row) << 10) + j];
            hreg[reg] = v;
            hout[row][np * 16 + r16] = (_Float16)v;
        }
    }
    __syncthreads();
    PUBLISH_SYNC(h16A, );
    load_weights(wB, Whh_e, j, kh, kg);

    // ---- encoder: 512 steps ----
    run_phase<false>(b0, j0, bt, jt, j, np, kh, kg, r16, tid, lane, wB, hreg,
                     h16A, h16B, Wih_e, bih_e, bhh_e, input, Wout, bout_v,
                     xpart, outp, tags, gcur, Als, red, hout, xv_s, xnp);

    // ---- bottleneck: features (16-way j reduction) + h0 ----
    {
        float we0 = Wenc[j], we1 = Wenc[H + j], we2 = Wenc[2 * H + j];
        if (kh == 0) {
#pragma unroll
            for (int reg = 0; reg < 4; ++reg) {
                float h = hreg[reg];
                float q0 = h * we0, q1 = h * we1, q2 = h * we2;
#pragma unroll
                for (int m = 1; m < 16; m <<= 1) {
                    q0 += __shfl_xor(q0, m);
                    q1 += __shfl_xor(q1, m);
                    q2 += __shfl_xor(q2, m);
                }
                if (r16 == 0) {
                    fp_np[np][kg * 4 + reg][0] = q0;
                    fp_np[np][kg * 4 + reg][1] = q1;
                    fp_np[np][kg * 4 + reg][2] = q2;
                }
            }
        }
        __syncthreads();
        if (tid < 48) {
            int bi = tid / 3, c = tid % 3;
            float s = fp_np[0][bi][c] + fp_np[1][bi][c] + fp_np[2][bi][c] + fp_np[3][bi][c];
            storef_coh(fpart + (size_t)(b0 + bi) * 48 + jt * 3 + c, s);
        }
        // sync (no h publish needed)
        if (tid >= 128 && tid < 144) {
            unsigned tgt = gcur + 1;
            while (__hip_atomic_load(&tags[(bt * 16 + (tid - 128)) * 32],
                                     __ATOMIC_RELAXED, __HIP_MEMORY_SCOPE_AGENT) < tgt)
                __builtin_amdgcn_s_sleep(1);
        }
        if (tid < 64) {
            asm volatile("s_waitcnt vmcnt(0)" ::: "memory");
            if (tid == 0)
                __hip_atomic_store(&tags[(bt * 16 + jt) * 32], gcur + 1,
                                   __ATOMIC_RELAXED, __HIP_MEMORY_SCOPE_AGENT);
        }
        __syncthreads();
        ++gcur;

        if (tid < 48) {
            int bi = tid / 3, c = tid % 3;
            float s = 0.f;
            const float* fp = fpart + (size_t)(b0 + bi) * 48 + c;
#pragma unroll
            for (int q = 0; q < 16; ++q) s += loadf_coh(fp + q * 3);
            float f = sigmoidf_(s + benc[c]);
            feats[bi][c] = f;
            if (jt == 0) featOut[(b0 + bi) * 3 + c] = f;
        }
        __syncthreads();

        // h0 = feats @ Wdec.T + bdec -> hreg + publish to h16A (decoder par0)
        if (kh == 0) {
#pragma unroll
            for (int reg = 0; reg < 4; ++reg) {
                int row = kg * 4 + reg;
                float v = feats[row][0] * Wdec[j * 3 + 0] + feats[row][1] * Wdec[j * 3 + 1] +
                          feats[row][2] * Wdec[j * 3 + 2] + bdec[j];
                hreg[reg] = v;
                hout[row][np * 16 + r16] = (_Float16)v;
            }
        }
        __syncthreads();
        PUBLISH_SYNC(h16A, );
        load_weights(wB, Whh_d, j, kh, kg);
    }

    // ---- decoder: 512 steps ----
    run_phase<true>(b0, j0, bt, jt, j, np, kh, kg, r16, tid, lane, wB, hreg,
                    h16A, h16B, Wih_d, bih_d, bhh_d, input, Wout, bout_v,
                    xpart, outp, tags, gcur, Als, red, hout, xv_s, xnp);

    // ---- final output column: x from step 511 (xpart slot 1, polled) ----
    if (jt == 0 && tid < 16) {
        const float* xp = xpart + 4096 + (size_t)(b0 + tid) * 16;
        float s = 0.f;
#pragma unroll
        for (int q = 0; q < 16; ++q) s += loadf_coh(xp + q);
        outp[(size_t)(b0 + tid) * T + (T - 1)] = s + bout_v;
    }
}

__global__ __launch_bounds__(256) void loss_partial(
    const float* __restrict__ input, const float* __restrict__ outp,
    float* __restrict__ partial)
{
    int idx = blockIdx.x * blockDim.x + threadIdx.x;
    float s = 0.f;
    for (int i = idx; i < B * T; i += gridDim.x * blockDim.x) {
        float d = input[i] - outp[i];
        s += d * d;
    }
#pragma unroll
    for (int off = 32; off; off >>= 1) s += __shfl_down(s, off);
    __shared__ float ws[4];
    if ((threadIdx.x & 63) == 0) ws[threadIdx.x >> 6] = s;
    __syncthreads();
    if (threadIdx.x == 0) partial[blockIdx.x] = ws[0] + ws[1] + ws[2] + ws[3];
}

__global__ __launch_bounds__(256) void loss_final(
    const float* __restrict__ partial, float* __restrict__ loss)
{
    int tid = threadIdx.x;
    float s = partial[tid];
#pragma unroll
    for (int off = 32; off; off >>= 1) s += __shfl_down(s, off);
    __shared__ float ws[4];
    if ((tid & 63) == 0) ws[tid >> 6] = s;
    __syncthreads();
    if (tid == 0) loss[0] = (ws[0] + ws[1] + ws[2] + ws[3]) * (1.0f / (float)(B * T));
}

extern "C" void kernel_launch(void* const* d_in, const int* in_sizes, int n_in,
                              void* d_out, int out_size, void* d_ws, size_t ws_size,
                              hipStream_t stream) {
    const float* input = (const float*)d_in[0];
    const float* h_init = (const float*)d_in[1];
    const float* Wih_e = (const float*)d_in[2];
    const float* Whh_e = (const float*)d_in[3];
    const float* bih_e = (const float*)d_in[4];
    const float* bhh_e = (const float*)d_in[5];
    const float* Wenc  = (const float*)d_in[6];
    const float* benc  = (const float*)d_in[7];
    const float* Wdec  = (const float*)d_in[8];
    const float* bdec  = (const float*)d_in[9];
    const float* Wih_d = (const float*)d_in[10];
    const float* Whh_d = (const float*)d_in[11];
    const float* bih_d = (const float*)d_in[12];
    const float* bhh_d = (const float*)d_in[13];
    const float* Wout  = (const float*)d_in[14];
    const float* bout  = (const float*)d_in[15];
    (void)in_sizes; (void)n_in; (void)out_size; (void)ws_size;

    float* out = (float*)d_out;
    float* lossp = out;                    // [1]
    float* feat = out + 1;                 // [B*3]
    float* outp = out + 1 + B * 3;         // [B*T]

    // ---- workspace layout ----
    char* ws = (char*)d_ws;
    _Float16* h16A = (_Float16*)ws;                  ws += (size_t)B * H * 2;
    _Float16* h16B = (_Float16*)ws;                  ws += (size_t)B * H * 2;
    float* xpart = (float*)ws;                       ws += 2 * 4096 * 4;   // [2][256][16]
    float* fpart = (float*)ws;                       ws += (size_t)B * 48 * 4;
    float* partial = (float*)ws;                     ws += 256 * 4;
    unsigned* tags = (unsigned*)ws;                  ws += 16 * 16 * 32 * 4;  // padded tag lines

    // tags must start at 0 every call (ws poisoned once, not restored)
    hipMemsetAsync(tags, 0, 16 * 16 * 32 * 4, stream);

    gru_persistent<<<dim3(NBLK), dim3(512), 0, stream>>>(
        input, h_init, Wih_e, Whh_e, bih_e, bhh_e, Wenc, benc, Wdec, bdec,
        Wih_d, Whh_d, bih_d, bhh_d, Wout, bout,
        feat, outp, h16A, h16B, xpart, fpart, tags);

    loss_partial<<<256, 256, 0, stream>>>(input, outp, partial);
    loss_final<<<1, 256, 0, stream>>>(partial, lossp);
}